// Round 1
// baseline (276.651 us; speedup 1.0000x reference)
//
#include <hip/hip_runtime.h>

#define Bn 4
#define Cn 64
#define Hn 256
#define Wn 256
#define HWn 65536

typedef __attribute__((ext_vector_type(8))) short bf16x8;
typedef __attribute__((ext_vector_type(4))) float f32x4;

__device__ __forceinline__ unsigned short f2b(float f) {
    union { float f; unsigned u; } v; v.f = f;
    return (unsigned short)(v.u >> 16);
}
__device__ __forceinline__ float b2f(unsigned short s) {
    union { float f; unsigned u; } v; v.u = ((unsigned)s) << 16;
    return v.f;
}

// ---------------- K1: 1x1 conv projections ----------------
// grid = B*H, block = 256 (one (b,h) row, thread = w)
__global__ __launch_bounds__(256) void k_proj(
    const float* __restrict__ x,
    const float* __restrict__ Wq, const float* __restrict__ bq,
    const float* __restrict__ Wk, const float* __restrict__ bk,
    const float* __restrict__ Wv, const float* __restrict__ bv,
    float* __restrict__ q_row, float* __restrict__ k_row,
    float* __restrict__ qT, float* __restrict__ kT,
    unsigned short* __restrict__ v_row)
{
    __shared__ float sWq[512], sWk[512], sWv[4096], sb[80];
    int t = threadIdx.x;
    int bid = blockIdx.x;
    int b = bid >> 8, h = bid & 255;
    for (int i = t; i < 512; i += 256) { sWq[i] = Wq[i]; sWk[i] = Wk[i]; }
    for (int i = t; i < 4096; i += 256) sWv[i] = Wv[i];
    if (t < 8) { sb[t] = bq[t]; sb[8 + t] = bk[t]; }
    if (t < 64) sb[16 + t] = bv[t];
    __syncthreads();

    float xr[64];
    const float* xp = x + (size_t)b * Cn * HWn + (size_t)h * Wn + t;
    #pragma unroll
    for (int c = 0; c < 64; ++c) xr[c] = xp[(size_t)c * HWn];

    float qv[8], kv[8];
    #pragma unroll
    for (int o = 0; o < 8; ++o) {
        float sq = sb[o], sk = sb[8 + o];
        #pragma unroll
        for (int c = 0; c < 64; ++c) { sq += sWq[o * 64 + c] * xr[c]; sk += sWk[o * 64 + c] * xr[c]; }
        qv[o] = sq; kv[o] = sk;
    }
    size_t roff = ((size_t)(b * Hn + h) * Wn + t) * 8;
    size_t toff = ((size_t)(b * Wn + t) * Hn + h) * 8;
    f32x4 q0 = {qv[0], qv[1], qv[2], qv[3]}, q1 = {qv[4], qv[5], qv[6], qv[7]};
    f32x4 k0 = {kv[0], kv[1], kv[2], kv[3]}, k1 = {kv[4], kv[5], kv[6], kv[7]};
    *(f32x4*)(q_row + roff) = q0; *(f32x4*)(q_row + roff + 4) = q1;
    *(f32x4*)(k_row + roff) = k0; *(f32x4*)(k_row + roff + 4) = k1;
    *(f32x4*)(qT + toff) = q0;    *(f32x4*)(qT + toff + 4) = q1;
    *(f32x4*)(kT + toff) = k0;    *(f32x4*)(kT + toff + 4) = k1;

    unsigned short* vp = v_row + (size_t)b * Cn * HWn + (size_t)h * Wn + t;
    #pragma unroll 8
    for (int o = 0; o < 64; ++o) {
        float s = sb[16 + o];
        #pragma unroll
        for (int c = 0; c < 64; ++c) s += sWv[o * 64 + c] * xr[c];
        vp[(size_t)o * HWn] = f2b(s);
    }
}

// ---------------- bf16 tiled transpose: in[b][r][c] -> out[b][c][r] ----------------
__global__ __launch_bounds__(256) void k_tr_bf16(
    const unsigned short* __restrict__ in, unsigned short* __restrict__ out,
    int R, int Ccols)
{
    __shared__ unsigned short tile[64][66];
    int t = threadIdx.x;
    int lr = t >> 6, lc = t & 63;
    int tilesC = Ccols >> 6;
    int per_b = (R >> 6) * tilesC;
    int bid = blockIdx.x;
    int b = bid / per_b;
    int rem = bid - b * per_b;
    int r0 = (rem / tilesC) << 6;
    int c0 = (rem - (rem / tilesC) * tilesC) << 6;
    const unsigned short* ip = in + (size_t)b * R * Ccols;
    unsigned short* op = out + (size_t)b * R * Ccols;
    #pragma unroll
    for (int i = 0; i < 16; ++i) {
        int r = lr * 16 + i;
        tile[r][lc] = ip[(size_t)(r0 + r) * Ccols + c0 + lc];
    }
    __syncthreads();
    #pragma unroll
    for (int i = 0; i < 16; ++i) {
        int c = lr * 16 + i;
        op[(size_t)(c0 + c) * R + r0 + lc] = tile[lc][c];
    }
}

// ---------------- K2: H-direction attention (per (b,w) column) ----------------
// E_H[h,j] = sum_c Q[h,c]K[j,c], diag masked; stats m,s; O_H = V @ P^T (unnormalized)
__global__ __launch_bounds__(256) void k_attnH(
    const float* __restrict__ qT, const float* __restrict__ kT,
    const unsigned short* __restrict__ vT,
    unsigned short* __restrict__ ohT,
    float* __restrict__ mH, float* __restrict__ sH)
{
    __shared__ float Qs[256][9];
    __shared__ float Ks[256][8];
    __shared__ __align__(16) unsigned short Ps[16384]; // 64 x 256 bf16, XOR swizzled
    __shared__ float red[2][4][64];
    int t = threadIdx.x, lane = t & 63, wv = t >> 6;
    int bid = blockIdx.x, b = bid >> 8, w = bid & 255;

    const float* qp = qT + ((size_t)(b * Wn + w)) * Hn * 8;
    const float* kp = kT + ((size_t)(b * Wn + w)) * Hn * 8;
    {
        const f32x4* q4 = (const f32x4*)qp;
        const f32x4* k4 = (const f32x4*)kp;
        f32x4 a0 = q4[t * 2], a1 = q4[t * 2 + 1];
        f32x4 b0 = k4[t * 2], b1 = k4[t * 2 + 1];
        Qs[t][0] = a0[0]; Qs[t][1] = a0[1]; Qs[t][2] = a0[2]; Qs[t][3] = a0[3];
        Qs[t][4] = a1[0]; Qs[t][5] = a1[1]; Qs[t][6] = a1[2]; Qs[t][7] = a1[3];
        Ks[t][0] = b0[0]; Ks[t][1] = b0[1]; Ks[t][2] = b0[2]; Ks[t][3] = b0[3];
        Ks[t][4] = b1[0]; Ks[t][5] = b1[1]; Ks[t][6] = b1[2]; Ks[t][7] = b1[3];
    }
    // V fragments (A operand), wave wv owns c in [wv*16, wv*16+16)
    const unsigned short* vp = vT + ((size_t)(b * Wn + w)) * Cn * Hn
                             + (size_t)(wv * 16 + (lane & 15)) * Hn + ((lane >> 4) * 8);
    bf16x8 vfrag[8];
    #pragma unroll
    for (int kt = 0; kt < 8; ++kt) vfrag[kt] = *(const bf16x8*)(vp + kt * 32);
    __syncthreads();

    #pragma unroll 1
    for (int ch = 0; ch < 4; ++ch) {
        int hl = lane;
        int h = ch * 64 + hl;
        float Qr[8];
        #pragma unroll
        for (int c = 0; c < 8; ++c) Qr[c] = Qs[h][c];
        float e[64];
        float mloc = -3.0e38f;
        #pragma unroll
        for (int jj = 0; jj < 64; ++jj) {
            int j = wv * 64 + jj;
            float s = Qr[0] * Ks[j][0];
            #pragma unroll
            for (int c = 1; c < 8; ++c) s += Qr[c] * Ks[j][c];
            s = (j == h) ? -1e30f : s;
            e[jj] = s;
            mloc = fmaxf(mloc, s);
        }
        red[0][wv][hl] = mloc;
        __syncthreads();
        float m = fmaxf(fmaxf(red[0][0][hl], red[0][1][hl]),
                        fmaxf(red[0][2][hl], red[0][3][hl]));
        float ssum = 0.f;
        unsigned base = (unsigned)hl * 512;
        unsigned swz = ((unsigned)(hl & 7)) << 4;
        #pragma unroll
        for (int jj = 0; jj < 64; jj += 2) {
            float p0 = __expf(e[jj] - m);
            float p1 = __expf(e[jj + 1] - m);
            ssum += p0 + p1;
            union { float f; unsigned u; } c0, c1; c0.f = p0; c1.f = p1;
            unsigned pk = (c0.u >> 16) | (c1.u & 0xffff0000u);
            unsigned bo = (base + (unsigned)((wv * 64 + jj) * 2)) ^ swz;
            *(unsigned*)((char*)Ps + bo) = pk;
        }
        red[1][wv][hl] = ssum;
        __syncthreads();
        float stot = red[1][0][hl] + red[1][1][hl] + red[1][2][hl] + red[1][3][hl];
        if (wv == 0) {
            size_t soff = ((size_t)(b * Wn + w)) * Hn + h;
            mH[soff] = m; sH[soff] = stot;
        }
        // O_H tile: D[c_local, h_local] += V(c,j) * P^T(j,h)
        #pragma unroll
        for (int nt = 0; nt < 4; ++nt) {
            f32x4 acc = {0.f, 0.f, 0.f, 0.f};
            int hb = nt * 16 + (lane & 15);
            unsigned swz2 = ((unsigned)(hb & 7)) << 4;
            #pragma unroll
            for (int kt = 0; kt < 8; ++kt) {
                unsigned bo = ((unsigned)hb * 512 + (unsigned)((kt * 32 + (lane >> 4) * 8) * 2)) ^ swz2;
                bf16x8 bfrag = *(const bf16x8*)((const char*)Ps + bo);
                acc = __builtin_amdgcn_mfma_f32_16x16x32_bf16(vfrag[kt], bfrag, acc, 0, 0, 0);
            }
            #pragma unroll
            for (int r = 0; r < 4; ++r) {
                int c = wv * 16 + (lane >> 4) * 4 + r;
                int hh = ch * 64 + nt * 16 + (lane & 15);
                ohT[((size_t)(b * Wn + w) * Cn + c) * Hn + hh] = f2b(acc[r]);
            }
        }
        __syncthreads();
    }
}

// ---------------- K3: W-direction attention + joint-softmax combine (per (b,h) row) ----------------
__global__ __launch_bounds__(256) void k_attnWC(
    const float* __restrict__ q_row, const float* __restrict__ k_row,
    const unsigned short* __restrict__ v_row,
    const unsigned short* __restrict__ oh_row,
    const float* __restrict__ mH, const float* __restrict__ sH,
    const float* __restrict__ x, const float* __restrict__ gamma,
    float* __restrict__ out)
{
    __shared__ float Qs[256][9];
    __shared__ float Ks[256][8];
    __shared__ __align__(16) unsigned short Ps[16384];
    __shared__ float red[2][4][64];
    __shared__ float scalI[64], scalF[64];
    int t = threadIdx.x, lane = t & 63, wv = t >> 6;
    int bid = blockIdx.x, b = bid >> 8, h = bid & 255;

    const float* qp = q_row + ((size_t)(b * Hn + h)) * Wn * 8;
    const float* kp = k_row + ((size_t)(b * Hn + h)) * Wn * 8;
    {
        const f32x4* q4 = (const f32x4*)qp;
        const f32x4* k4 = (const f32x4*)kp;
        f32x4 a0 = q4[t * 2], a1 = q4[t * 2 + 1];
        f32x4 b0 = k4[t * 2], b1 = k4[t * 2 + 1];
        Qs[t][0] = a0[0]; Qs[t][1] = a0[1]; Qs[t][2] = a0[2]; Qs[t][3] = a0[3];
        Qs[t][4] = a1[0]; Qs[t][5] = a1[1]; Qs[t][6] = a1[2]; Qs[t][7] = a1[3];
        Ks[t][0] = b0[0]; Ks[t][1] = b0[1]; Ks[t][2] = b0[2]; Ks[t][3] = b0[3];
        Ks[t][4] = b1[0]; Ks[t][5] = b1[1]; Ks[t][6] = b1[2]; Ks[t][7] = b1[3];
    }
    const unsigned short* vp = v_row
        + ((size_t)(b * Cn + wv * 16 + (lane & 15)) * Hn + h) * Wn + ((lane >> 4) * 8);
    bf16x8 vfrag[8];
    #pragma unroll
    for (int kt = 0; kt < 8; ++kt) vfrag[kt] = *(const bf16x8*)(vp + kt * 32);
    float g = gamma[0];
    __syncthreads();

    #pragma unroll 1
    for (int ch = 0; ch < 4; ++ch) {
        int wl = lane;
        int w = ch * 64 + wl;
        float Qr[8];
        #pragma unroll
        for (int c = 0; c < 8; ++c) Qr[c] = Qs[w][c];
        float e[64];
        float mloc = -3.0e38f;
        #pragma unroll
        for (int jj = 0; jj < 64; ++jj) {
            int j = wv * 64 + jj;
            float s = Qr[0] * Ks[j][0];
            #pragma unroll
            for (int c = 1; c < 8; ++c) s += Qr[c] * Ks[j][c];
            e[jj] = s;
            mloc = fmaxf(mloc, s);
        }
        red[0][wv][wl] = mloc;
        __syncthreads();
        float mw = fmaxf(fmaxf(red[0][0][wl], red[0][1][wl]),
                         fmaxf(red[0][2][wl], red[0][3][wl]));
        size_t soff = ((size_t)(b * Wn + w)) * Hn + h;
        float mh = mH[soff], sh = sH[soff];
        float m = fmaxf(mw, mh);
        float ssum = 0.f;
        unsigned base = (unsigned)wl * 512;
        unsigned swz = ((unsigned)(wl & 7)) << 4;
        #pragma unroll
        for (int jj = 0; jj < 64; jj += 2) {
            float p0 = __expf(e[jj] - m);
            float p1 = __expf(e[jj + 1] - m);
            ssum += p0 + p1;
            union { float f; unsigned u; } c0, c1; c0.f = p0; c1.f = p1;
            unsigned pk = (c0.u >> 16) | (c1.u & 0xffff0000u);
            unsigned bo = (base + (unsigned)((wv * 64 + jj) * 2)) ^ swz;
            *(unsigned*)((char*)Ps + bo) = pk;
        }
        red[1][wv][wl] = ssum;
        __syncthreads();
        float swt = red[1][0][wl] + red[1][1][wl] + red[1][2][wl] + red[1][3][wl];
        float stot = swt + sh * __expf(mh - m);
        if (wv == 0) {
            float inv = 1.0f / stot;
            scalI[wl] = inv;
            scalF[wl] = __expf(mh - m) * inv;
        }
        __syncthreads();
        #pragma unroll
        for (int nt = 0; nt < 4; ++nt) {
            f32x4 acc = {0.f, 0.f, 0.f, 0.f};
            int wb = nt * 16 + (lane & 15);
            unsigned swz2 = ((unsigned)(wb & 7)) << 4;
            #pragma unroll
            for (int kt = 0; kt < 8; ++kt) {
                unsigned bo = ((unsigned)wb * 512 + (unsigned)((kt * 32 + (lane >> 4) * 8) * 2)) ^ swz2;
                bf16x8 bfrag = *(const bf16x8*)((const char*)Ps + bo);
                acc = __builtin_amdgcn_mfma_f32_16x16x32_bf16(vfrag[kt], bfrag, acc, 0, 0, 0);
            }
            float sI = scalI[nt * 16 + (lane & 15)];
            float sF = scalF[nt * 16 + (lane & 15)];
            #pragma unroll
            for (int r = 0; r < 4; ++r) {
                int c = wv * 16 + (lane >> 4) * 4 + r;
                int wc = ch * 64 + nt * 16 + (lane & 15);
                size_t idx = ((size_t)(b * Cn + c) * Hn + h) * Wn + wc;
                float oh = b2f(oh_row[idx]);
                out[idx] = g * (acc[r] * sI + oh * sF) + x[idx];
            }
        }
        __syncthreads();
    }
}

extern "C" void kernel_launch(void* const* d_in, const int* in_sizes, int n_in,
                              void* d_out, int out_size, void* d_ws, size_t ws_size,
                              hipStream_t stream) {
    const float* x  = (const float*)d_in[0];
    const float* Wq = (const float*)d_in[1];
    const float* bq = (const float*)d_in[2];
    const float* Wk = (const float*)d_in[3];
    const float* bk = (const float*)d_in[4];
    const float* Wv = (const float*)d_in[5];
    const float* bv = (const float*)d_in[6];
    const float* gm = (const float*)d_in[7];
    float* out = (float*)d_out;
    char* ws = (char*)d_ws;

    const size_t BHW = (size_t)Bn * Hn * Wn; // 262144
    float* q_row = (float*)ws;
    float* k_row = q_row + 8 * BHW;
    float* qT    = k_row + 8 * BHW;
    float* kT    = qT + 8 * BHW;
    unsigned short* v_row = (unsigned short*)(kT + 8 * BHW);
    unsigned short* vT    = v_row + 64 * BHW;
    unsigned short* ohT   = vT + 64 * BHW;
    unsigned short* oh_row = vT; // alias: vT is dead after k_attnH
    float* mHb = (float*)(ohT + 64 * BHW);
    float* sHb = mHb + BHW;

    k_proj<<<Bn * Hn, 256, 0, stream>>>(x, Wq, bq, Wk, bk, Wv, bv,
                                        q_row, k_row, qT, kT, v_row);
    k_tr_bf16<<<Bn * (16384 / 64) * (256 / 64), 256, 0, stream>>>(v_row, vT, 16384, 256);
    k_attnH<<<Bn * Wn, 256, 0, stream>>>(qT, kT, vT, ohT, mHb, sHb);
    k_tr_bf16<<<Bn * (256 / 64) * (16384 / 64), 256, 0, stream>>>(ohT, oh_row, 256, 16384);
    k_attnWC<<<Bn * Hn, 256, 0, stream>>>(q_row, k_row, v_row, oh_row, mHb, sHb, x, gm, out);
}

// Round 2
// 247.233 us; speedup vs baseline: 1.1190x; 1.1190x over previous
//
#include <hip/hip_runtime.h>

#define Bn 4
#define Cn 64
#define Hn 256
#define Wn 256
#define HWn 65536

typedef __attribute__((ext_vector_type(8))) short bf16x8;
typedef __attribute__((ext_vector_type(4))) float f32x4;

__device__ __forceinline__ unsigned short f2b(float f) {
    union { float f; unsigned u; } v; v.f = f;
    return (unsigned short)(v.u >> 16);
}
__device__ __forceinline__ float b2f(unsigned short s) {
    union { float f; unsigned u; } v; v.u = ((unsigned)s) << 16;
    return v.f;
}

// ---------------- K1: 1x1 conv projections ----------------
// grid = B*H, block = 256 (one (b,h) row, thread = w).
// Weights read with wave-uniform indices -> compiler emits s_load into SGPRs;
// v_fmac consumes SGPR operand directly. No LDS at all (R1: LDS-broadcast
// weight reads were the issue-port bottleneck: 163us, VALUBusy 29%).
__global__ __launch_bounds__(256) void k_proj(
    const float* __restrict__ x,
    const float* __restrict__ Wq, const float* __restrict__ bq,
    const float* __restrict__ Wk, const float* __restrict__ bk,
    const float* __restrict__ Wv, const float* __restrict__ bv,
    float* __restrict__ q_row, float* __restrict__ k_row,
    float* __restrict__ qT, float* __restrict__ kT,
    unsigned short* __restrict__ v_row)
{
    int t = threadIdx.x;
    int bid = blockIdx.x;
    int b = bid >> 8, h = bid & 255;

    float xr[64];
    const float* xp = x + (size_t)b * Cn * HWn + (size_t)h * Wn + t;
    #pragma unroll
    for (int c = 0; c < 64; ++c) xr[c] = xp[(size_t)c * HWn];

    float qv[8], kv[8];
    #pragma unroll
    for (int o = 0; o < 8; ++o) {
        float sq = bq[o], sk = bk[o];
        #pragma unroll
        for (int c = 0; c < 64; ++c) {
            sq += Wq[o * 64 + c] * xr[c];
            sk += Wk[o * 64 + c] * xr[c];
        }
        qv[o] = sq; kv[o] = sk;
    }
    size_t roff = ((size_t)(b * Hn + h) * Wn + t) * 8;
    size_t toff = ((size_t)(b * Wn + t) * Hn + h) * 8;
    f32x4 q0 = {qv[0], qv[1], qv[2], qv[3]}, q1 = {qv[4], qv[5], qv[6], qv[7]};
    f32x4 k0 = {kv[0], kv[1], kv[2], kv[3]}, k1 = {kv[4], kv[5], kv[6], kv[7]};
    *(f32x4*)(q_row + roff) = q0; *(f32x4*)(q_row + roff + 4) = q1;
    *(f32x4*)(k_row + roff) = k0; *(f32x4*)(k_row + roff + 4) = k1;
    *(f32x4*)(qT + toff) = q0;    *(f32x4*)(qT + toff + 4) = q1;
    *(f32x4*)(kT + toff) = k0;    *(f32x4*)(kT + toff + 4) = k1;

    unsigned short* vp = v_row + (size_t)b * Cn * HWn + (size_t)h * Wn + t;
    #pragma unroll 8
    for (int o = 0; o < 64; ++o) {
        float s = bv[o];
        #pragma unroll
        for (int c = 0; c < 64; ++c) s += Wv[o * 64 + c] * xr[c];
        vp[(size_t)o * HWn] = f2b(s);
    }
}

// ---------------- bf16 tiled transpose: in[b][r][c] -> out[b][c][r] ----------------
__global__ __launch_bounds__(256) void k_tr_bf16(
    const unsigned short* __restrict__ in, unsigned short* __restrict__ out,
    int R, int Ccols)
{
    __shared__ unsigned short tile[64][66];
    int t = threadIdx.x;
    int lr = t >> 6, lc = t & 63;
    int tilesC = Ccols >> 6;
    int per_b = (R >> 6) * tilesC;
    int bid = blockIdx.x;
    int b = bid / per_b;
    int rem = bid - b * per_b;
    int r0 = (rem / tilesC) << 6;
    int c0 = (rem - (rem / tilesC) * tilesC) << 6;
    const unsigned short* ip = in + (size_t)b * R * Ccols;
    unsigned short* op = out + (size_t)b * R * Ccols;
    #pragma unroll
    for (int i = 0; i < 16; ++i) {
        int r = lr * 16 + i;
        tile[r][lc] = ip[(size_t)(r0 + r) * Ccols + c0 + lc];
    }
    __syncthreads();
    #pragma unroll
    for (int i = 0; i < 16; ++i) {
        int c = lr * 16 + i;
        op[(size_t)(c0 + c) * R + r0 + lc] = tile[lc][c];
    }
}

// ---------------- K2: H-direction attention (per (b,w) column) ----------------
__global__ __launch_bounds__(256) void k_attnH(
    const float* __restrict__ qT, const float* __restrict__ kT,
    const unsigned short* __restrict__ vT,
    unsigned short* __restrict__ ohT,
    float* __restrict__ mH, float* __restrict__ sH)
{
    __shared__ float Qs[256][9];
    __shared__ float Ks[256][8];
    __shared__ __align__(16) unsigned short Ps[16384]; // 64 x 256 bf16, XOR swizzled
    __shared__ float red[2][4][64];
    int t = threadIdx.x, lane = t & 63, wv = t >> 6;
    int bid = blockIdx.x, b = bid >> 8, w = bid & 255;

    const float* qp = qT + ((size_t)(b * Wn + w)) * Hn * 8;
    const float* kp = kT + ((size_t)(b * Wn + w)) * Hn * 8;
    {
        const f32x4* q4 = (const f32x4*)qp;
        const f32x4* k4 = (const f32x4*)kp;
        f32x4 a0 = q4[t * 2], a1 = q4[t * 2 + 1];
        f32x4 b0 = k4[t * 2], b1 = k4[t * 2 + 1];
        Qs[t][0] = a0[0]; Qs[t][1] = a0[1]; Qs[t][2] = a0[2]; Qs[t][3] = a0[3];
        Qs[t][4] = a1[0]; Qs[t][5] = a1[1]; Qs[t][6] = a1[2]; Qs[t][7] = a1[3];
        Ks[t][0] = b0[0]; Ks[t][1] = b0[1]; Ks[t][2] = b0[2]; Ks[t][3] = b0[3];
        Ks[t][4] = b1[0]; Ks[t][5] = b1[1]; Ks[t][6] = b1[2]; Ks[t][7] = b1[3];
    }
    const unsigned short* vp = vT + ((size_t)(b * Wn + w)) * Cn * Hn
                             + (size_t)(wv * 16 + (lane & 15)) * Hn + ((lane >> 4) * 8);
    bf16x8 vfrag[8];
    #pragma unroll
    for (int kt = 0; kt < 8; ++kt) vfrag[kt] = *(const bf16x8*)(vp + kt * 32);
    __syncthreads();

    #pragma unroll 1
    for (int ch = 0; ch < 4; ++ch) {
        int hl = lane;
        int h = ch * 64 + hl;
        float Qr[8];
        #pragma unroll
        for (int c = 0; c < 8; ++c) Qr[c] = Qs[h][c];
        float e[64];
        float mloc = -3.0e38f;
        #pragma unroll
        for (int jj = 0; jj < 64; ++jj) {
            int j = wv * 64 + jj;
            float s = Qr[0] * Ks[j][0];
            #pragma unroll
            for (int c = 1; c < 8; ++c) s += Qr[c] * Ks[j][c];
            s = (j == h) ? -1e30f : s;
            e[jj] = s;
            mloc = fmaxf(mloc, s);
        }
        red[0][wv][hl] = mloc;
        __syncthreads();
        float m = fmaxf(fmaxf(red[0][0][hl], red[0][1][hl]),
                        fmaxf(red[0][2][hl], red[0][3][hl]));
        float ssum = 0.f;
        unsigned base = (unsigned)hl * 512;
        unsigned swz = ((unsigned)(hl & 7)) << 4;
        #pragma unroll
        for (int jj = 0; jj < 64; jj += 2) {
            float p0 = __expf(e[jj] - m);
            float p1 = __expf(e[jj + 1] - m);
            ssum += p0 + p1;
            union { float f; unsigned u; } c0, c1; c0.f = p0; c1.f = p1;
            unsigned pk = (c0.u >> 16) | (c1.u & 0xffff0000u);
            unsigned bo = (base + (unsigned)((wv * 64 + jj) * 2)) ^ swz;
            *(unsigned*)((char*)Ps + bo) = pk;
        }
        red[1][wv][hl] = ssum;
        __syncthreads();
        float stot = red[1][0][hl] + red[1][1][hl] + red[1][2][hl] + red[1][3][hl];
        if (wv == 0) {
            size_t soff = ((size_t)(b * Wn + w)) * Hn + h;
            mH[soff] = m; sH[soff] = stot;
        }
        #pragma unroll
        for (int nt = 0; nt < 4; ++nt) {
            f32x4 acc = {0.f, 0.f, 0.f, 0.f};
            int hb = nt * 16 + (lane & 15);
            unsigned swz2 = ((unsigned)(hb & 7)) << 4;
            #pragma unroll
            for (int kt = 0; kt < 8; ++kt) {
                unsigned bo = ((unsigned)hb * 512 + (unsigned)((kt * 32 + (lane >> 4) * 8) * 2)) ^ swz2;
                bf16x8 bfrag = *(const bf16x8*)((const char*)Ps + bo);
                acc = __builtin_amdgcn_mfma_f32_16x16x32_bf16(vfrag[kt], bfrag, acc, 0, 0, 0);
            }
            #pragma unroll
            for (int r = 0; r < 4; ++r) {
                int c = wv * 16 + (lane >> 4) * 4 + r;
                int hh = ch * 64 + nt * 16 + (lane & 15);
                ohT[((size_t)(b * Wn + w) * Cn + c) * Hn + hh] = f2b(acc[r]);
            }
        }
        __syncthreads();
    }
}

// ---------------- K3: W-direction attention + joint-softmax combine (per (b,h) row) ----------------
__global__ __launch_bounds__(256) void k_attnWC(
    const float* __restrict__ q_row, const float* __restrict__ k_row,
    const unsigned short* __restrict__ v_row,
    const unsigned short* __restrict__ oh_row,
    const float* __restrict__ mH, const float* __restrict__ sH,
    const float* __restrict__ x, const float* __restrict__ gamma,
    float* __restrict__ out)
{
    __shared__ float Qs[256][9];
    __shared__ float Ks[256][8];
    __shared__ __align__(16) unsigned short Ps[16384];
    __shared__ float red[2][4][64];
    __shared__ float scalI[64], scalF[64];
    int t = threadIdx.x, lane = t & 63, wv = t >> 6;
    int bid = blockIdx.x, b = bid >> 8, h = bid & 255;

    const float* qp = q_row + ((size_t)(b * Hn + h)) * Wn * 8;
    const float* kp = k_row + ((size_t)(b * Hn + h)) * Wn * 8;
    {
        const f32x4* q4 = (const f32x4*)qp;
        const f32x4* k4 = (const f32x4*)kp;
        f32x4 a0 = q4[t * 2], a1 = q4[t * 2 + 1];
        f32x4 b0 = k4[t * 2], b1 = k4[t * 2 + 1];
        Qs[t][0] = a0[0]; Qs[t][1] = a0[1]; Qs[t][2] = a0[2]; Qs[t][3] = a0[3];
        Qs[t][4] = a1[0]; Qs[t][5] = a1[1]; Qs[t][6] = a1[2]; Qs[t][7] = a1[3];
        Ks[t][0] = b0[0]; Ks[t][1] = b0[1]; Ks[t][2] = b0[2]; Ks[t][3] = b0[3];
        Ks[t][4] = b1[0]; Ks[t][5] = b1[1]; Ks[t][6] = b1[2]; Ks[t][7] = b1[3];
    }
    const unsigned short* vp = v_row
        + ((size_t)(b * Cn + wv * 16 + (lane & 15)) * Hn + h) * Wn + ((lane >> 4) * 8);
    bf16x8 vfrag[8];
    #pragma unroll
    for (int kt = 0; kt < 8; ++kt) vfrag[kt] = *(const bf16x8*)(vp + kt * 32);
    float g = gamma[0];
    __syncthreads();

    #pragma unroll 1
    for (int ch = 0; ch < 4; ++ch) {
        int wl = lane;
        int w = ch * 64 + wl;
        float Qr[8];
        #pragma unroll
        for (int c = 0; c < 8; ++c) Qr[c] = Qs[w][c];
        float e[64];
        float mloc = -3.0e38f;
        #pragma unroll
        for (int jj = 0; jj < 64; ++jj) {
            int j = wv * 64 + jj;
            float s = Qr[0] * Ks[j][0];
            #pragma unroll
            for (int c = 1; c < 8; ++c) s += Qr[c] * Ks[j][c];
            e[jj] = s;
            mloc = fmaxf(mloc, s);
        }
        red[0][wv][wl] = mloc;
        __syncthreads();
        float mw = fmaxf(fmaxf(red[0][0][wl], red[0][1][wl]),
                         fmaxf(red[0][2][wl], red[0][3][wl]));
        size_t soff = ((size_t)(b * Wn + w)) * Hn + h;
        float mh = mH[soff], sh = sH[soff];
        float m = fmaxf(mw, mh);
        float ssum = 0.f;
        unsigned base = (unsigned)wl * 512;
        unsigned swz = ((unsigned)(wl & 7)) << 4;
        #pragma unroll
        for (int jj = 0; jj < 64; jj += 2) {
            float p0 = __expf(e[jj] - m);
            float p1 = __expf(e[jj + 1] - m);
            ssum += p0 + p1;
            union { float f; unsigned u; } c0, c1; c0.f = p0; c1.f = p1;
            unsigned pk = (c0.u >> 16) | (c1.u & 0xffff0000u);
            unsigned bo = (base + (unsigned)((wv * 64 + jj) * 2)) ^ swz;
            *(unsigned*)((char*)Ps + bo) = pk;
        }
        red[1][wv][wl] = ssum;
        __syncthreads();
        float swt = red[1][0][wl] + red[1][1][wl] + red[1][2][wl] + red[1][3][wl];
        float stot = swt + sh * __expf(mh - m);
        if (wv == 0) {
            float inv = 1.0f / stot;
            scalI[wl] = inv;
            scalF[wl] = __expf(mh - m) * inv;
        }
        __syncthreads();
        #pragma unroll
        for (int nt = 0; nt < 4; ++nt) {
            f32x4 acc = {0.f, 0.f, 0.f, 0.f};
            int wb = nt * 16 + (lane & 15);
            unsigned swz2 = ((unsigned)(wb & 7)) << 4;
            #pragma unroll
            for (int kt = 0; kt < 8; ++kt) {
                unsigned bo = ((unsigned)wb * 512 + (unsigned)((kt * 32 + (lane >> 4) * 8) * 2)) ^ swz2;
                bf16x8 bfrag = *(const bf16x8*)((const char*)Ps + bo);
                acc = __builtin_amdgcn_mfma_f32_16x16x32_bf16(vfrag[kt], bfrag, acc, 0, 0, 0);
            }
            float sI = scalI[nt * 16 + (lane & 15)];
            float sF = scalF[nt * 16 + (lane & 15)];
            #pragma unroll
            for (int r = 0; r < 4; ++r) {
                int c = wv * 16 + (lane >> 4) * 4 + r;
                int wc = ch * 64 + nt * 16 + (lane & 15);
                size_t idx = ((size_t)(b * Cn + c) * Hn + h) * Wn + wc;
                float oh = b2f(oh_row[idx]);
                out[idx] = g * (acc[r] * sI + oh * sF) + x[idx];
            }
        }
        __syncthreads();
    }
}

extern "C" void kernel_launch(void* const* d_in, const int* in_sizes, int n_in,
                              void* d_out, int out_size, void* d_ws, size_t ws_size,
                              hipStream_t stream) {
    const float* x  = (const float*)d_in[0];
    const float* Wq = (const float*)d_in[1];
    const float* bq = (const float*)d_in[2];
    const float* Wk = (const float*)d_in[3];
    const float* bk = (const float*)d_in[4];
    const float* Wv = (const float*)d_in[5];
    const float* bv = (const float*)d_in[6];
    const float* gm = (const float*)d_in[7];
    float* out = (float*)d_out;
    char* ws = (char*)d_ws;

    const size_t BHW = (size_t)Bn * Hn * Wn; // 262144
    float* q_row = (float*)ws;
    float* k_row = q_row + 8 * BHW;
    float* qT    = k_row + 8 * BHW;
    float* kT    = qT + 8 * BHW;
    unsigned short* v_row = (unsigned short*)(kT + 8 * BHW);
    unsigned short* vT    = v_row + 64 * BHW;
    unsigned short* ohT   = vT + 64 * BHW;
    unsigned short* oh_row = vT; // alias: vT is dead after k_attnH
    float* mHb = (float*)(ohT + 64 * BHW);
    float* sHb = mHb + BHW;

    k_proj<<<Bn * Hn, 256, 0, stream>>>(x, Wq, bq, Wk, bk, Wv, bv,
                                        q_row, k_row, qT, kT, v_row);
    k_tr_bf16<<<Bn * (16384 / 64) * (256 / 64), 256, 0, stream>>>(v_row, vT, 16384, 256);
    k_attnH<<<Bn * Wn, 256, 0, stream>>>(qT, kT, vT, ohT, mHb, sHb);
    k_tr_bf16<<<Bn * (256 / 64) * (16384 / 64), 256, 0, stream>>>(ohT, oh_row, 256, 16384);
    k_attnWC<<<Bn * Hn, 256, 0, stream>>>(q_row, k_row, v_row, oh_row, mHb, sHb, x, gm, out);
}

// Round 3
// 167.371 us; speedup vs baseline: 1.6529x; 1.4772x over previous
//
#include <hip/hip_runtime.h>

#define Bn 4
#define Cn 64
#define Hn 256
#define Wn 256
#define HWn 65536

typedef __attribute__((ext_vector_type(8))) short bf16x8;
typedef __attribute__((ext_vector_type(4))) float f32x4;

__device__ __forceinline__ unsigned short f2b(float f) {
    union { float f; unsigned u; } v; v.f = f;
    return (unsigned short)(v.u >> 16);
}
__device__ __forceinline__ float b2f(unsigned short s) {
    union { float f; unsigned u; } v; v.u = ((unsigned)s) << 16;
    return v.f;
}

// ---------------- K1: 1x1 conv projections via MFMA ----------------
// GEMM: W_comb[80][64] x x[64][HW].  M-tiles: m=0 -> q(rows 0-7)+k(rows 8-15),
// m=1..4 -> v channels.  All weights live in 40 VGPRs/wave (A-fragments),
// reused across 16 pixel tiles.  B-fragments load direct from global x
// (each 16-lane group reads 64B contiguous; every x element read once/block).
// R2 lesson: per-thread FMA needed 5120 weight fetches/thread -> s_load
// lgkmcnt stalls (VALUBusy 14%). MFMA amortizes weights into registers.
__global__ __launch_bounds__(256) void k_proj(
    const float* __restrict__ x,
    const float* __restrict__ Wq, const float* __restrict__ bq,
    const float* __restrict__ Wk, const float* __restrict__ bk,
    const float* __restrict__ Wv, const float* __restrict__ bv,
    float* __restrict__ q_row, float* __restrict__ k_row,
    float* __restrict__ qT, float* __restrict__ kT,
    unsigned short* __restrict__ v_row)
{
    int t = threadIdx.x, lane = t & 63, wv = t >> 6;
    int bid = blockIdx.x, b = bid >> 8, h = bid & 255;
    int row16 = lane & 15, g = lane >> 4;

    // A-fragments: lane holds row (lane&15), k = g*8 + i (+32 per k-step)
    bf16x8 Af[5][2];
    #pragma unroll
    for (int m = 0; m < 5; ++m) {
        const float* wrow;
        if (m == 0) wrow = (row16 < 8) ? (Wq + row16 * 64) : (Wk + (row16 - 8) * 64);
        else        wrow = Wv + (size_t)((m - 1) * 16 + row16) * 64;
        #pragma unroll
        for (int ks = 0; ks < 2; ++ks) {
            int c0 = ks * 32 + g * 8;
            f32x4 w0 = *(const f32x4*)(wrow + c0);
            f32x4 w1 = *(const f32x4*)(wrow + c0 + 4);
            bf16x8 a;
            a[0] = (short)f2b(w0[0]); a[1] = (short)f2b(w0[1]);
            a[2] = (short)f2b(w0[2]); a[3] = (short)f2b(w0[3]);
            a[4] = (short)f2b(w1[0]); a[5] = (short)f2b(w1[1]);
            a[6] = (short)f2b(w1[2]); a[7] = (short)f2b(w1[3]);
            Af[m][ks] = a;
        }
    }

    f32x4 acc[5][4];
    #pragma unroll
    for (int m = 0; m < 5; ++m)
        #pragma unroll
        for (int nt = 0; nt < 4; ++nt)
            acc[m][nt] = (f32x4){0.f, 0.f, 0.f, 0.f};

    const float* xb = x + (size_t)b * Cn * HWn + (size_t)h * Wn;
    #pragma unroll
    for (int nt = 0; nt < 4; ++nt) {
        int p = wv * 64 + nt * 16 + row16;
        #pragma unroll
        for (int ks = 0; ks < 2; ++ks) {
            int c0 = ks * 32 + g * 8;
            bf16x8 bf;
            #pragma unroll
            for (int i = 0; i < 8; ++i)
                bf[i] = (short)f2b(xb[(size_t)(c0 + i) * HWn + p]);
            #pragma unroll
            for (int m = 0; m < 5; ++m)
                acc[m][nt] = __builtin_amdgcn_mfma_f32_16x16x32_bf16(Af[m][ks], bf, acc[m][nt], 0, 0, 0);
        }
    }

    // Epilogue. C/D: col = lane&15 (pixel), row = g*4 + r.
    f32x4 bQK = (g < 2) ? *(const f32x4*)(bq + g * 4)
                        : *(const f32x4*)(bk + (g - 2) * 4);
    #pragma unroll
    for (int nt = 0; nt < 4; ++nt) {
        int p = wv * 64 + nt * 16 + row16;
        // m = 0: q (rows 0-7) / k (rows 8-15), fp32, both layouts
        f32x4 d = acc[0][nt];
        d[0] += bQK[0]; d[1] += bQK[1]; d[2] += bQK[2]; d[3] += bQK[3];
        size_t roff = ((size_t)(b * Hn + h) * Wn + p) * 8 + (size_t)(g & 1) * 4;
        size_t toff = ((size_t)(b * Wn + p) * Hn + h) * 8 + (size_t)(g & 1) * 4;
        if (g < 2) { *(f32x4*)(q_row + roff) = d; *(f32x4*)(qT + toff) = d; }
        else       { *(f32x4*)(k_row + roff) = d; *(f32x4*)(kT + toff) = d; }
        // m = 1..4: v channels, bf16
        #pragma unroll
        for (int m = 1; m < 5; ++m) {
            f32x4 bV = *(const f32x4*)(bv + (m - 1) * 16 + g * 4);
            unsigned short* vp = v_row + (size_t)b * Cn * HWn
                               + (size_t)((m - 1) * 16 + g * 4) * HWn
                               + (size_t)h * Wn + p;
            #pragma unroll
            for (int r = 0; r < 4; ++r)
                vp[(size_t)r * HWn] = f2b(acc[m][nt][r] + bV[r]);
        }
    }
}

// ---------------- bf16 tiled transpose: in[b][r][c] -> out[b][c][r] ----------------
__global__ __launch_bounds__(256) void k_tr_bf16(
    const unsigned short* __restrict__ in, unsigned short* __restrict__ out,
    int R, int Ccols)
{
    __shared__ unsigned short tile[64][66];
    int t = threadIdx.x;
    int lr = t >> 6, lc = t & 63;
    int tilesC = Ccols >> 6;
    int per_b = (R >> 6) * tilesC;
    int bid = blockIdx.x;
    int b = bid / per_b;
    int rem = bid - b * per_b;
    int r0 = (rem / tilesC) << 6;
    int c0 = (rem - (rem / tilesC) * tilesC) << 6;
    const unsigned short* ip = in + (size_t)b * R * Ccols;
    unsigned short* op = out + (size_t)b * R * Ccols;
    #pragma unroll
    for (int i = 0; i < 16; ++i) {
        int r = lr * 16 + i;
        tile[r][lc] = ip[(size_t)(r0 + r) * Ccols + c0 + lc];
    }
    __syncthreads();
    #pragma unroll
    for (int i = 0; i < 16; ++i) {
        int c = lr * 16 + i;
        op[(size_t)(c0 + c) * R + r0 + lc] = tile[lc][c];
    }
}

// ---------------- K2: H-direction attention (per (b,w) column) ----------------
__global__ __launch_bounds__(256) void k_attnH(
    const float* __restrict__ qT, const float* __restrict__ kT,
    const unsigned short* __restrict__ vT,
    unsigned short* __restrict__ ohT,
    float* __restrict__ mH, float* __restrict__ sH)
{
    __shared__ float Qs[256][9];
    __shared__ float Ks[256][8];
    __shared__ __align__(16) unsigned short Ps[16384]; // 64 x 256 bf16, XOR swizzled
    __shared__ float red[2][4][64];
    int t = threadIdx.x, lane = t & 63, wv = t >> 6;
    int bid = blockIdx.x, b = bid >> 8, w = bid & 255;

    const float* qp = qT + ((size_t)(b * Wn + w)) * Hn * 8;
    const float* kp = kT + ((size_t)(b * Wn + w)) * Hn * 8;
    {
        const f32x4* q4 = (const f32x4*)qp;
        const f32x4* k4 = (const f32x4*)kp;
        f32x4 a0 = q4[t * 2], a1 = q4[t * 2 + 1];
        f32x4 b0 = k4[t * 2], b1 = k4[t * 2 + 1];
        Qs[t][0] = a0[0]; Qs[t][1] = a0[1]; Qs[t][2] = a0[2]; Qs[t][3] = a0[3];
        Qs[t][4] = a1[0]; Qs[t][5] = a1[1]; Qs[t][6] = a1[2]; Qs[t][7] = a1[3];
        Ks[t][0] = b0[0]; Ks[t][1] = b0[1]; Ks[t][2] = b0[2]; Ks[t][3] = b0[3];
        Ks[t][4] = b1[0]; Ks[t][5] = b1[1]; Ks[t][6] = b1[2]; Ks[t][7] = b1[3];
    }
    const unsigned short* vp = vT + ((size_t)(b * Wn + w)) * Cn * Hn
                             + (size_t)(wv * 16 + (lane & 15)) * Hn + ((lane >> 4) * 8);
    bf16x8 vfrag[8];
    #pragma unroll
    for (int kt = 0; kt < 8; ++kt) vfrag[kt] = *(const bf16x8*)(vp + kt * 32);
    __syncthreads();

    #pragma unroll 1
    for (int ch = 0; ch < 4; ++ch) {
        int hl = lane;
        int h = ch * 64 + hl;
        float Qr[8];
        #pragma unroll
        for (int c = 0; c < 8; ++c) Qr[c] = Qs[h][c];
        float e[64];
        float mloc = -3.0e38f;
        #pragma unroll
        for (int jj = 0; jj < 64; ++jj) {
            int j = wv * 64 + jj;
            float s = Qr[0] * Ks[j][0];
            #pragma unroll
            for (int c = 1; c < 8; ++c) s += Qr[c] * Ks[j][c];
            s = (j == h) ? -1e30f : s;
            e[jj] = s;
            mloc = fmaxf(mloc, s);
        }
        red[0][wv][hl] = mloc;
        __syncthreads();
        float m = fmaxf(fmaxf(red[0][0][hl], red[0][1][hl]),
                        fmaxf(red[0][2][hl], red[0][3][hl]));
        float ssum = 0.f;
        unsigned base = (unsigned)hl * 512;
        unsigned swz = ((unsigned)(hl & 7)) << 4;
        #pragma unroll
        for (int jj = 0; jj < 64; jj += 2) {
            float p0 = __expf(e[jj] - m);
            float p1 = __expf(e[jj + 1] - m);
            ssum += p0 + p1;
            union { float f; unsigned u; } c0, c1; c0.f = p0; c1.f = p1;
            unsigned pk = (c0.u >> 16) | (c1.u & 0xffff0000u);
            unsigned bo = (base + (unsigned)((wv * 64 + jj) * 2)) ^ swz;
            *(unsigned*)((char*)Ps + bo) = pk;
        }
        red[1][wv][hl] = ssum;
        __syncthreads();
        float stot = red[1][0][hl] + red[1][1][hl] + red[1][2][hl] + red[1][3][hl];
        if (wv == 0) {
            size_t soff = ((size_t)(b * Wn + w)) * Hn + h;
            mH[soff] = m; sH[soff] = stot;
        }
        #pragma unroll
        for (int nt = 0; nt < 4; ++nt) {
            f32x4 acc = {0.f, 0.f, 0.f, 0.f};
            int hb = nt * 16 + (lane & 15);
            unsigned swz2 = ((unsigned)(hb & 7)) << 4;
            #pragma unroll
            for (int kt = 0; kt < 8; ++kt) {
                unsigned bo = ((unsigned)hb * 512 + (unsigned)((kt * 32 + (lane >> 4) * 8) * 2)) ^ swz2;
                bf16x8 bfrag = *(const bf16x8*)((const char*)Ps + bo);
                acc = __builtin_amdgcn_mfma_f32_16x16x32_bf16(vfrag[kt], bfrag, acc, 0, 0, 0);
            }
            #pragma unroll
            for (int r = 0; r < 4; ++r) {
                int c = wv * 16 + (lane >> 4) * 4 + r;
                int hh = ch * 64 + nt * 16 + (lane & 15);
                ohT[((size_t)(b * Wn + w) * Cn + c) * Hn + hh] = f2b(acc[r]);
            }
        }
        __syncthreads();
    }
}

// ---------------- K3: W-direction attention + joint-softmax combine (per (b,h) row) ----------------
__global__ __launch_bounds__(256) void k_attnWC(
    const float* __restrict__ q_row, const float* __restrict__ k_row,
    const unsigned short* __restrict__ v_row,
    const unsigned short* __restrict__ oh_row,
    const float* __restrict__ mH, const float* __restrict__ sH,
    const float* __restrict__ x, const float* __restrict__ gamma,
    float* __restrict__ out)
{
    __shared__ float Qs[256][9];
    __shared__ float Ks[256][8];
    __shared__ __align__(16) unsigned short Ps[16384];
    __shared__ float red[2][4][64];
    __shared__ float scalI[64], scalF[64];
    int t = threadIdx.x, lane = t & 63, wv = t >> 6;
    int bid = blockIdx.x, b = bid >> 8, h = bid & 255;

    const float* qp = q_row + ((size_t)(b * Hn + h)) * Wn * 8;
    const float* kp = k_row + ((size_t)(b * Hn + h)) * Wn * 8;
    {
        const f32x4* q4 = (const f32x4*)qp;
        const f32x4* k4 = (const f32x4*)kp;
        f32x4 a0 = q4[t * 2], a1 = q4[t * 2 + 1];
        f32x4 b0 = k4[t * 2], b1 = k4[t * 2 + 1];
        Qs[t][0] = a0[0]; Qs[t][1] = a0[1]; Qs[t][2] = a0[2]; Qs[t][3] = a0[3];
        Qs[t][4] = a1[0]; Qs[t][5] = a1[1]; Qs[t][6] = a1[2]; Qs[t][7] = a1[3];
        Ks[t][0] = b0[0]; Ks[t][1] = b0[1]; Ks[t][2] = b0[2]; Ks[t][3] = b0[3];
        Ks[t][4] = b1[0]; Ks[t][5] = b1[1]; Ks[t][6] = b1[2]; Ks[t][7] = b1[3];
    }
    const unsigned short* vp = v_row
        + ((size_t)(b * Cn + wv * 16 + (lane & 15)) * Hn + h) * Wn + ((lane >> 4) * 8);
    bf16x8 vfrag[8];
    #pragma unroll
    for (int kt = 0; kt < 8; ++kt) vfrag[kt] = *(const bf16x8*)(vp + kt * 32);
    float g = gamma[0];
    __syncthreads();

    #pragma unroll 1
    for (int ch = 0; ch < 4; ++ch) {
        int wl = lane;
        int w = ch * 64 + wl;
        float Qr[8];
        #pragma unroll
        for (int c = 0; c < 8; ++c) Qr[c] = Qs[w][c];
        float e[64];
        float mloc = -3.0e38f;
        #pragma unroll
        for (int jj = 0; jj < 64; ++jj) {
            int j = wv * 64 + jj;
            float s = Qr[0] * Ks[j][0];
            #pragma unroll
            for (int c = 1; c < 8; ++c) s += Qr[c] * Ks[j][c];
            e[jj] = s;
            mloc = fmaxf(mloc, s);
        }
        red[0][wv][wl] = mloc;
        __syncthreads();
        float mw = fmaxf(fmaxf(red[0][0][wl], red[0][1][wl]),
                         fmaxf(red[0][2][wl], red[0][3][wl]));
        size_t soff = ((size_t)(b * Wn + w)) * Hn + h;
        float mh = mH[soff], sh = sH[soff];
        float m = fmaxf(mw, mh);
        float ssum = 0.f;
        unsigned base = (unsigned)wl * 512;
        unsigned swz = ((unsigned)(wl & 7)) << 4;
        #pragma unroll
        for (int jj = 0; jj < 64; jj += 2) {
            float p0 = __expf(e[jj] - m);
            float p1 = __expf(e[jj + 1] - m);
            ssum += p0 + p1;
            union { float f; unsigned u; } c0, c1; c0.f = p0; c1.f = p1;
            unsigned pk = (c0.u >> 16) | (c1.u & 0xffff0000u);
            unsigned bo = (base + (unsigned)((wv * 64 + jj) * 2)) ^ swz;
            *(unsigned*)((char*)Ps + bo) = pk;
        }
        red[1][wv][wl] = ssum;
        __syncthreads();
        float swt = red[1][0][wl] + red[1][1][wl] + red[1][2][wl] + red[1][3][wl];
        float stot = swt + sh * __expf(mh - m);
        if (wv == 0) {
            float inv = 1.0f / stot;
            scalI[wl] = inv;
            scalF[wl] = __expf(mh - m) * inv;
        }
        __syncthreads();
        #pragma unroll
        for (int nt = 0; nt < 4; ++nt) {
            f32x4 acc = {0.f, 0.f, 0.f, 0.f};
            int wb = nt * 16 + (lane & 15);
            unsigned swz2 = ((unsigned)(wb & 7)) << 4;
            #pragma unroll
            for (int kt = 0; kt < 8; ++kt) {
                unsigned bo = ((unsigned)wb * 512 + (unsigned)((kt * 32 + (lane >> 4) * 8) * 2)) ^ swz2;
                bf16x8 bfrag = *(const bf16x8*)((const char*)Ps + bo);
                acc = __builtin_amdgcn_mfma_f32_16x16x32_bf16(vfrag[kt], bfrag, acc, 0, 0, 0);
            }
            float sI = scalI[nt * 16 + (lane & 15)];
            float sF = scalF[nt * 16 + (lane & 15)];
            #pragma unroll
            for (int r = 0; r < 4; ++r) {
                int c = wv * 16 + (lane >> 4) * 4 + r;
                int wc = ch * 64 + nt * 16 + (lane & 15);
                size_t idx = ((size_t)(b * Cn + c) * Hn + h) * Wn + wc;
                float oh = b2f(oh_row[idx]);
                out[idx] = g * (acc[r] * sI + oh * sF) + x[idx];
            }
        }
        __syncthreads();
    }
}

extern "C" void kernel_launch(void* const* d_in, const int* in_sizes, int n_in,
                              void* d_out, int out_size, void* d_ws, size_t ws_size,
                              hipStream_t stream) {
    const float* x  = (const float*)d_in[0];
    const float* Wq = (const float*)d_in[1];
    const float* bq = (const float*)d_in[2];
    const float* Wk = (const float*)d_in[3];
    const float* bk = (const float*)d_in[4];
    const float* Wv = (const float*)d_in[5];
    const float* bv = (const float*)d_in[6];
    const float* gm = (const float*)d_in[7];
    float* out = (float*)d_out;
    char* ws = (char*)d_ws;

    const size_t BHW = (size_t)Bn * Hn * Wn; // 262144
    float* q_row = (float*)ws;
    float* k_row = q_row + 8 * BHW;
    float* qT    = k_row + 8 * BHW;
    float* kT    = qT + 8 * BHW;
    unsigned short* v_row = (unsigned short*)(kT + 8 * BHW);
    unsigned short* vT    = v_row + 64 * BHW;
    unsigned short* ohT   = vT + 64 * BHW;
    unsigned short* oh_row = vT; // alias: vT is dead after k_attnH
    float* mHb = (float*)(ohT + 64 * BHW);
    float* sHb = mHb + BHW;

    k_proj<<<Bn * Hn, 256, 0, stream>>>(x, Wq, bq, Wk, bk, Wv, bv,
                                        q_row, k_row, qT, kT, v_row);
    k_tr_bf16<<<Bn * (16384 / 64) * (256 / 64), 256, 0, stream>>>(v_row, vT, 16384, 256);
    k_attnH<<<Bn * Wn, 256, 0, stream>>>(qT, kT, vT, ohT, mHb, sHb);
    k_tr_bf16<<<Bn * (256 / 64) * (16384 / 64), 256, 0, stream>>>(ohT, oh_row, 256, 16384);
    k_attnWC<<<Bn * Hn, 256, 0, stream>>>(q_row, k_row, v_row, oh_row, mHb, sHb, x, gm, out);
}

// Round 4
// 125.029 us; speedup vs baseline: 2.2127x; 1.3387x over previous
//
#include <hip/hip_runtime.h>

#define Bn 4
#define Cn 64
#define Hn 256
#define Wn 256
#define HWn 65536

typedef unsigned int u32;
typedef __attribute__((ext_vector_type(8))) short bf16x8;
typedef __attribute__((ext_vector_type(4))) float f32x4;
typedef __attribute__((ext_vector_type(16))) float f32x16;

__device__ __forceinline__ unsigned short f2b(float f) {
    union { float f; unsigned u; } v; v.f = f;
    return (unsigned short)(v.u >> 16);
}
__device__ __forceinline__ float b2f(unsigned short s) {
    union { float f; unsigned u; } v; v.u = ((unsigned)s) << 16;
    return v.f;
}
__device__ __forceinline__ u32 cvtpk(float lo, float hi) {
    u32 r;
    asm("v_cvt_pk_bf16_f32 %0, %1, %2" : "=v"(r) : "v"(lo), "v"(hi));
    return r;
}
// v_permlane32_swap_b32: a' = [a.low | b from lane-32], b' = [a from lane+32 | b.high]
__device__ __forceinline__ void vswap(u32& a, u32& b) {
    asm volatile("v_permlane32_swap_b32 %0, %1" : "+v"(a), "+v"(b));
}
__device__ __forceinline__ float pair_other(float v, int lane) {
    union { float f; u32 u; } A; A.f = v;
    u32 a = A.u, b = A.u;
    vswap(a, b);
    union { u32 u; float f; } R; R.u = (lane < 32) ? b : a;
    return R.f;
}
// P-fragment for one 16-wide k-step from 8 lane-local p values (rows pattern
// {0,1,2,3,8,9,10,11}+4*hi): after cvt_pk + permlane32_swap each lane holds
// the 4 B-frag words (k-slots (hi*8)+0..7) in order.
__device__ __forceinline__ bf16x8 buildP(const float* p) {
    u32 A = cvtpk(p[0], p[1]), B = cvtpk(p[4], p[5]);
    u32 C = cvtpk(p[2], p[3]), D = cvtpk(p[6], p[7]);
    vswap(A, B); vswap(C, D);
    union { u32 w[4]; bf16x8 v; } u;
    u.w[0] = A; u.w[1] = C; u.w[2] = B; u.w[3] = D;
    return u.v;
}

// ---------------- K1: 1x1 conv projections via MFMA ----------------
// q/k now written as bf16 (attn consumes them as MFMA frags directly).
__global__ __launch_bounds__(256) void k_proj(
    const float* __restrict__ x,
    const float* __restrict__ Wq, const float* __restrict__ bq,
    const float* __restrict__ Wk, const float* __restrict__ bk,
    const float* __restrict__ Wv, const float* __restrict__ bv,
    unsigned short* __restrict__ qbr, unsigned short* __restrict__ kbr,
    unsigned short* __restrict__ qbT, unsigned short* __restrict__ kbT,
    unsigned short* __restrict__ v_row)
{
    int t = threadIdx.x, lane = t & 63, wv = t >> 6;
    int bid = blockIdx.x, b = bid >> 8, h = bid & 255;
    int row16 = lane & 15, g = lane >> 4;

    bf16x8 Af[5][2];
    #pragma unroll
    for (int m = 0; m < 5; ++m) {
        const float* wrow;
        if (m == 0) wrow = (row16 < 8) ? (Wq + row16 * 64) : (Wk + (row16 - 8) * 64);
        else        wrow = Wv + (size_t)((m - 1) * 16 + row16) * 64;
        #pragma unroll
        for (int ks = 0; ks < 2; ++ks) {
            int c0 = ks * 32 + g * 8;
            f32x4 w0 = *(const f32x4*)(wrow + c0);
            f32x4 w1 = *(const f32x4*)(wrow + c0 + 4);
            bf16x8 a;
            a[0] = (short)f2b(w0[0]); a[1] = (short)f2b(w0[1]);
            a[2] = (short)f2b(w0[2]); a[3] = (short)f2b(w0[3]);
            a[4] = (short)f2b(w1[0]); a[5] = (short)f2b(w1[1]);
            a[6] = (short)f2b(w1[2]); a[7] = (short)f2b(w1[3]);
            Af[m][ks] = a;
        }
    }

    f32x4 acc[5][4];
    #pragma unroll
    for (int m = 0; m < 5; ++m)
        #pragma unroll
        for (int nt = 0; nt < 4; ++nt)
            acc[m][nt] = (f32x4){0.f, 0.f, 0.f, 0.f};

    const float* xb = x + (size_t)b * Cn * HWn + (size_t)h * Wn;
    #pragma unroll
    for (int nt = 0; nt < 4; ++nt) {
        int p = wv * 64 + nt * 16 + row16;
        #pragma unroll
        for (int ks = 0; ks < 2; ++ks) {
            int c0 = ks * 32 + g * 8;
            bf16x8 bf;
            #pragma unroll
            for (int i = 0; i < 8; ++i)
                bf[i] = (short)f2b(xb[(size_t)(c0 + i) * HWn + p]);
            #pragma unroll
            for (int m = 0; m < 5; ++m)
                acc[m][nt] = __builtin_amdgcn_mfma_f32_16x16x32_bf16(Af[m][ks], bf, acc[m][nt], 0, 0, 0);
        }
    }

    f32x4 bQK = (g < 2) ? *(const f32x4*)(bq + g * 4)
                        : *(const f32x4*)(bk + (g - 2) * 4);
    #pragma unroll
    for (int nt = 0; nt < 4; ++nt) {
        int p = wv * 64 + nt * 16 + row16;
        f32x4 d = acc[0][nt];
        d[0] += bQK[0]; d[1] += bQK[1]; d[2] += bQK[2]; d[3] += bQK[3];
        u32 w0 = (u32)f2b(d[0]) | ((u32)f2b(d[1]) << 16);
        u32 w1 = (u32)f2b(d[2]) | ((u32)f2b(d[3]) << 16);
        size_t roff = ((size_t)(b * Hn + h) * Wn + p) * 8 + (size_t)((g & 1) * 4);
        size_t toff = ((size_t)(b * Wn + p) * Hn + h) * 8 + (size_t)((g & 1) * 4);
        if (g < 2) {
            *(u32*)(qbr + roff) = w0; *(u32*)(qbr + roff + 2) = w1;
            *(u32*)(qbT + toff) = w0; *(u32*)(qbT + toff + 2) = w1;
        } else {
            *(u32*)(kbr + roff) = w0; *(u32*)(kbr + roff + 2) = w1;
            *(u32*)(kbT + toff) = w0; *(u32*)(kbT + toff + 2) = w1;
        }
        #pragma unroll
        for (int m = 1; m < 5; ++m) {
            f32x4 bV = *(const f32x4*)(bv + (m - 1) * 16 + g * 4);
            unsigned short* vp = v_row + (size_t)b * Cn * HWn
                               + (size_t)((m - 1) * 16 + g * 4) * HWn
                               + (size_t)h * Wn + p;
            #pragma unroll
            for (int r = 0; r < 4; ++r)
                vp[(size_t)r * HWn] = f2b(acc[m][nt][r] + bV[r]);
        }
    }
}

// ---------------- bf16 tiled transpose: in[b][r][c] -> out[b][c][r] ----------------
__global__ __launch_bounds__(256) void k_tr_bf16(
    const unsigned short* __restrict__ in, unsigned short* __restrict__ out,
    int R, int Ccols)
{
    __shared__ unsigned short tile[64][66];
    int t = threadIdx.x;
    int lr = t >> 6, lc = t & 63;
    int tilesC = Ccols >> 6;
    int per_b = (R >> 6) * tilesC;
    int bid = blockIdx.x;
    int b = bid / per_b;
    int rem = bid - b * per_b;
    int r0 = (rem / tilesC) << 6;
    int c0 = (rem - (rem / tilesC) * tilesC) << 6;
    const unsigned short* ip = in + (size_t)b * R * Ccols;
    unsigned short* op = out + (size_t)b * R * Ccols;
    #pragma unroll
    for (int i = 0; i < 16; ++i) {
        int r = lr * 16 + i;
        tile[r][lc] = ip[(size_t)(r0 + r) * Ccols + c0 + lc];
    }
    __syncthreads();
    #pragma unroll
    for (int i = 0; i < 16; ++i) {
        int c = lr * 16 + i;
        op[(size_t)(c0 + c) * R + r0 + lc] = tile[lc][c];
    }
}

// ---------------- K2: H-direction attention, swapped-MFMA flash structure ----------------
// Per (b,w) column. E[j][q=h] via mfma(K,Q); in-register online softmax
// (pair-merge via permlane32_swap, defer-max THR=8); PV via mfma(V,P).
// V staged in LDS with (c&7)<<4 XOR swizzle -> conflict-free b128 both ways.
__global__ __launch_bounds__(256, 2) void k_attnH(
    const unsigned short* __restrict__ qT, const unsigned short* __restrict__ kT,
    const unsigned short* __restrict__ vT,
    unsigned short* __restrict__ ohT,
    float* __restrict__ mH, float* __restrict__ sH)
{
    __shared__ __align__(16) unsigned short Vl[16384];
    int t = threadIdx.x, lane = t & 63, wv = t >> 6;
    int l31 = lane & 31, hi = lane >> 5;
    int bid = blockIdx.x, b = bid >> 8, w = bid & 255;

    // stage V plane [c][h] (contiguous 32KB), swizzled
    const char* vsrc = (const char*)(vT + ((size_t)(b * Wn + w)) * Cn * Hn);
    #pragma unroll
    for (int p = 0; p < 8; ++p) {
        int lin = p * 4096 + t * 16;
        int c = lin >> 9;
        f32x4 d = *(const f32x4*)(vsrc + lin);
        unsigned dst = (unsigned)lin ^ ((unsigned)(c & 7) << 4);
        *(f32x4*)((char*)Vl + dst) = d;
    }

    const unsigned short* qb = qT + ((size_t)(b * Wn + w)) * Hn * 8;
    const unsigned short* kb = kT + ((size_t)(b * Wn + w)) * Hn * 8;
    bf16x8 zer = {};
    bf16x8 Qf[2], Kf[8];
    #pragma unroll
    for (int qt = 0; qt < 2; ++qt) {
        int q = (wv * 2 + qt) * 32 + l31;
        bf16x8 v = *(const bf16x8*)(qb + (size_t)q * 8);
        Qf[qt] = (hi == 0) ? v : zer;
    }
    #pragma unroll
    for (int jt = 0; jt < 8; ++jt) {
        int j = jt * 32 + l31;
        bf16x8 v = *(const bf16x8*)(kb + (size_t)j * 8);
        Kf[jt] = (hi == 0) ? v : zer;
    }
    __syncthreads();

    #pragma unroll
    for (int qt = 0; qt < 2; ++qt) {
        int qtA = wv * 2 + qt;
        int q = qtA * 32 + l31;
        f32x16 Oa = {}, Ob = {};
        float m = -3.0e38f, s = 0.f;
        #pragma unroll
        for (int jt = 0; jt < 8; ++jt) {
            f32x16 zc = {};
            f32x16 e = __builtin_amdgcn_mfma_f32_32x32x16_bf16(Kf[jt], Qf[qt], zc, 0, 0, 0);
            if (jt == qtA) {  // diagonal mask: row j == col q
                #pragma unroll
                for (int r = 0; r < 16; ++r) {
                    int rl = (r & 3) + 8 * (r >> 2) + 4 * hi;
                    e[r] = (rl == l31) ? -1e30f : e[r];
                }
            }
            float pm = e[0];
            #pragma unroll
            for (int r = 1; r < 16; ++r) pm = fmaxf(pm, e[r]);
            pm = fmaxf(pm, pair_other(pm, lane));
            if (!__all(pm <= m + 8.0f)) {
                float mn = fmaxf(m, pm);
                float f = __expf(m - mn);
                #pragma unroll
                for (int r = 0; r < 16; ++r) { Oa[r] *= f; Ob[r] *= f; }
                s *= f; m = mn;
            }
            float p[16];
            float ss = 0.f;
            #pragma unroll
            for (int r = 0; r < 16; ++r) { p[r] = __expf(e[r] - m); ss += p[r]; }
            s += ss;
            bf16x8 P0 = buildP(p);
            bf16x8 P1 = buildP(p + 8);
            #pragma unroll
            for (int k2 = 0; k2 < 2; ++k2) {
                int ktA = jt * 2 + k2;
                bf16x8 Pf = k2 ? P1 : P0;
                #pragma unroll
                for (int ct = 0; ct < 2; ++ct) {
                    int c = ct * 32 + l31;
                    unsigned ad = ((unsigned)(c * 512 + ktA * 32 + hi * 16))
                                ^ ((unsigned)(c & 7) << 4);
                    bf16x8 Vf = *(const bf16x8*)((const char*)Vl + ad);
                    if (ct == 0) Oa = __builtin_amdgcn_mfma_f32_32x32x16_bf16(Vf, Pf, Oa, 0, 0, 0);
                    else         Ob = __builtin_amdgcn_mfma_f32_32x32x16_bf16(Vf, Pf, Ob, 0, 0, 0);
                }
            }
        }
        float s_tot = s + pair_other(s, lane);
        if (hi == 0) {
            size_t so = ((size_t)(b * Wn + w)) * Hn + q;
            mH[so] = m; sH[so] = s_tot;
        }
        unsigned short* ob = ohT + ((size_t)(b * Wn + w)) * Cn * Hn;
        #pragma unroll
        for (int ct = 0; ct < 2; ++ct) {
            #pragma unroll
            for (int r = 0; r < 16; ++r) {
                int c = (r & 3) + 8 * (r >> 2) + 4 * hi + ct * 32;
                float val = ct ? Ob[r] : Oa[r];
                ob[(size_t)c * Hn + q] = f2b(val);
            }
        }
    }
}

// ---------------- K3: W-direction attention + joint combine ----------------
__global__ __launch_bounds__(256, 2) void k_attnW(
    const unsigned short* __restrict__ qbr, const unsigned short* __restrict__ kbr,
    const unsigned short* __restrict__ v_row,
    const unsigned short* __restrict__ oh_row,
    const float* __restrict__ mH, const float* __restrict__ sH,
    const float* __restrict__ x, const float* __restrict__ gamma,
    float* __restrict__ out)
{
    __shared__ __align__(16) unsigned short Vl[16384];
    int t = threadIdx.x, lane = t & 63, wv = t >> 6;
    int l31 = lane & 31, hi = lane >> 5;
    int bid = blockIdx.x, b = bid >> 8, h = bid & 255;

    // stage V plane [c][w] (rows strided by HWn), swizzled
    #pragma unroll
    for (int p = 0; p < 8; ++p) {
        int lin = p * 4096 + t * 16;
        int c = lin >> 9, off = lin & 511;
        const char* src = (const char*)(v_row + ((size_t)(b * Cn + c)) * HWn + (size_t)h * Wn) + off;
        f32x4 d = *(const f32x4*)src;
        unsigned dst = (unsigned)lin ^ ((unsigned)(c & 7) << 4);
        *(f32x4*)((char*)Vl + dst) = d;
    }

    const unsigned short* qb = qbr + ((size_t)(b * Hn + h)) * Wn * 8;
    const unsigned short* kb = kbr + ((size_t)(b * Hn + h)) * Wn * 8;
    bf16x8 zer = {};
    bf16x8 Qf[2], Kf[8];
    #pragma unroll
    for (int qt = 0; qt < 2; ++qt) {
        int q = (wv * 2 + qt) * 32 + l31;
        bf16x8 v = *(const bf16x8*)(qb + (size_t)q * 8);
        Qf[qt] = (hi == 0) ? v : zer;
    }
    #pragma unroll
    for (int jt = 0; jt < 8; ++jt) {
        int j = jt * 32 + l31;
        bf16x8 v = *(const bf16x8*)(kb + (size_t)j * 8);
        Kf[jt] = (hi == 0) ? v : zer;
    }
    float g = gamma[0];
    __syncthreads();

    #pragma unroll
    for (int qt = 0; qt < 2; ++qt) {
        int q = (wv * 2 + qt) * 32 + l31;
        f32x16 Oa = {}, Ob = {};
        float m = -3.0e38f, s = 0.f;
        #pragma unroll
        for (int jt = 0; jt < 8; ++jt) {
            f32x16 zc = {};
            f32x16 e = __builtin_amdgcn_mfma_f32_32x32x16_bf16(Kf[jt], Qf[qt], zc, 0, 0, 0);
            float pm = e[0];
            #pragma unroll
            for (int r = 1; r < 16; ++r) pm = fmaxf(pm, e[r]);
            pm = fmaxf(pm, pair_other(pm, lane));
            if (!__all(pm <= m + 8.0f)) {
                float mn = fmaxf(m, pm);
                float f = __expf(m - mn);
                #pragma unroll
                for (int r = 0; r < 16; ++r) { Oa[r] *= f; Ob[r] *= f; }
                s *= f; m = mn;
            }
            float p[16];
            float ss = 0.f;
            #pragma unroll
            for (int r = 0; r < 16; ++r) { p[r] = __expf(e[r] - m); ss += p[r]; }
            s += ss;
            bf16x8 P0 = buildP(p);
            bf16x8 P1 = buildP(p + 8);
            #pragma unroll
            for (int k2 = 0; k2 < 2; ++k2) {
                int ktA = jt * 2 + k2;
                bf16x8 Pf = k2 ? P1 : P0;
                #pragma unroll
                for (int ct = 0; ct < 2; ++ct) {
                    int c = ct * 32 + l31;
                    unsigned ad = ((unsigned)(c * 512 + ktA * 32 + hi * 16))
                                ^ ((unsigned)(c & 7) << 4);
                    bf16x8 Vf = *(const bf16x8*)((const char*)Vl + ad);
                    if (ct == 0) Oa = __builtin_amdgcn_mfma_f32_32x32x16_bf16(Vf, Pf, Oa, 0, 0, 0);
                    else         Ob = __builtin_amdgcn_mfma_f32_32x32x16_bf16(Vf, Pf, Ob, 0, 0, 0);
                }
            }
        }
        float s_tot = s + pair_other(s, lane);
        size_t so = ((size_t)(b * Wn + q)) * Hn + h;
        float mh = mH[so], sh = sH[so];
        float M = fmaxf(m, mh);
        float eW = __expf(m - M), eH = __expf(mh - M);
        float inv = 1.0f / (s_tot * eW + sh * eH);
        float sI = eW * inv, sF = eH * inv;
        #pragma unroll
        for (int ct = 0; ct < 2; ++ct) {
            #pragma unroll
            for (int r = 0; r < 16; ++r) {
                int c = (r & 3) + 8 * (r >> 2) + 4 * hi + ct * 32;
                size_t idx = ((size_t)(b * Cn + c) * Hn + h) * Wn + q;
                float val = ct ? Ob[r] : Oa[r];
                out[idx] = g * (val * sI + b2f(oh_row[idx]) * sF) + x[idx];
            }
        }
    }
}

extern "C" void kernel_launch(void* const* d_in, const int* in_sizes, int n_in,
                              void* d_out, int out_size, void* d_ws, size_t ws_size,
                              hipStream_t stream) {
    const float* x  = (const float*)d_in[0];
    const float* Wq = (const float*)d_in[1];
    const float* bq = (const float*)d_in[2];
    const float* Wk = (const float*)d_in[3];
    const float* bk = (const float*)d_in[4];
    const float* Wv = (const float*)d_in[5];
    const float* bv = (const float*)d_in[6];
    const float* gm = (const float*)d_in[7];
    float* out = (float*)d_out;
    char* ws = (char*)d_ws;

    const size_t BHW = (size_t)Bn * Hn * Wn; // 262144
    unsigned short* qbr = (unsigned short*)ws;
    unsigned short* kbr = qbr + 8 * BHW;
    unsigned short* qbT = kbr + 8 * BHW;
    unsigned short* kbT = qbT + 8 * BHW;
    unsigned short* v_row = kbT + 8 * BHW;
    unsigned short* vT    = v_row + 64 * BHW;
    unsigned short* ohT   = vT + 64 * BHW;
    unsigned short* oh_row = vT; // alias: vT dead after k_attnH
    float* mHb = (float*)(ohT + 64 * BHW);
    float* sHb = mHb + BHW;

    k_proj<<<Bn * Hn, 256, 0, stream>>>(x, Wq, bq, Wk, bk, Wv, bv,
                                        qbr, kbr, qbT, kbT, v_row);
    k_tr_bf16<<<Bn * (16384 / 64) * (256 / 64), 256, 0, stream>>>(v_row, vT, 16384, 256);
    k_attnH<<<Bn * Wn, 256, 0, stream>>>(qbT, kbT, vT, ohT, mHb, sHb);
    k_tr_bf16<<<Bn * (256 / 64) * (16384 / 64), 256, 0, stream>>>(ohT, oh_row, 256, 16384);
    k_attnW<<<Bn * Hn, 256, 0, stream>>>(qbr, kbr, v_row, oh_row, mHb, sHb, x, gm, out);
}